// Round 13
// baseline (29.153 us; speedup 1.0000x reference)
//
#include <hip/hip_runtime.h>

// Problem constants (from reference): B=32, S=256, C=50, L=20, F=30, W=3
constexpr int Bc = 32;
constexpr int Sc = 256;
constexpr int Cc = 50;
constexpr int Lc = 20;
constexpr int Fc = 30;
constexpr int Wc = 3;
constexpr int OUT_CH   = Cc * Fc;       // 1500
constexpr int CONV_LEN = Lc - Wc + 1;   // 18
constexpr int XSZ      = Cc * Lc;       // 1000 floats per (b,s)
constexpr int BLOCK    = 512;           // 8 waves/block (R8 shell - best so far)
constexpr int CH_PER_T = 3;             // 3t..3t+2 never crosses a group boundary
constexpr int NP       = 8;             // positions per block -> 1024 blocks
constexpr int ACT      = OUT_CH / CH_PER_T;   // 500 active compute lanes
constexpr int STG      = XSZ / 4;             // 250 stager lanes (float4 each)

// Barrier with lgkmcnt(0) only: retires this wave's own ds ops (RAW visibility
// + WAR on shared buffers); global prefetch loads stay in flight across it.
static __device__ __forceinline__ void block_sync() {
    asm volatile("s_waitcnt lgkmcnt(0)" ::: "memory");
    __builtin_amdgcn_s_barrier();
    asm volatile("" ::: "memory");
}

// (512, 8): 8 waves/EU min -> compiler must fit <=64 VGPR; LDS 8KB not limiting.
__global__ __launch_bounds__(BLOCK, 8)
void charcnn_kernel(const float* __restrict__ x,      // [B*S, C, L]
                    const float* __restrict__ weight, // [C*F, 1, W]
                    const float* __restrict__ bias,   // [C*F]
                    float* __restrict__ out)          // [B*S, C*F]
{
    __shared__ float xs[2][XSZ];        // double-buffered 4 KB slabs

    const int t    = threadIdx.x;
    const int pos0 = blockIdx.x * NP;
    const bool on  = (t < ACT);         // 500 compute lanes
    const bool stg = (t < STG);         // 250 staging lanes

    // ---- ANTI-PHASE-LOCK STAGGER: all blocks launch simultaneously and run
    // identical-period phase loops, so the whole GPU's load/store bursts
    // phase-lock (correlated stalls: R3 showed VALUBusy=28% with ~8 waves/SIMD,
    // impossible unless stalls are correlated). Spread block start times over
    // ~one position-period (8 x 1024 cyc ~ 3.4 us max, avg 1.5 us).
    {
        const int phase = blockIdx.x & 7;
        #pragma unroll 1
        for (int i = 0; i < phase; ++i)
            __builtin_amdgcn_s_sleep(16);       // 16*64 = 1024 cycles each
    }

    // ---- weights/bias once per thread: 9 + 3 scalars (register-lean)
    float w[CH_PER_T * Wc];             // 9 floats at weight + 9t
    float bb[CH_PER_T];
    if (on) {
        const float* wp = weight + t * (CH_PER_T * Wc);
        #pragma unroll
        for (int i = 0; i < CH_PER_T * Wc; ++i) w[i] = wp[i];
        const float* bp = bias + t * CH_PER_T;
        #pragma unroll
        for (int i = 0; i < CH_PER_T; ++i) bb[i] = bp[i];
    }

    const int c = t / 10;               // group shared by this thread's 3 channels

    // ---- prologue: stage slab0 into xs[0]
    if (stg)
        ((float4*)xs[0])[t] = ((const float4*)(x + (size_t)pos0 * XSZ))[t];
    block_sync();

    #pragma unroll 2                    // static buf indices, modest code size
    for (int p = 0; p < NP; ++p) {
        const int buf = p & 1;

        // Issue next slab's load FIRST: latency hides under this position's compute.
        float4 preA;
        if (stg && (p + 1 < NP))
            preA = ((const float4*)(x + (size_t)(pos0 + p + 1) * XSZ))[t];

        if (on) {
            // Row: 80 B, 16B-aligned -> 5x ds_read_b128 (10 lanes share a row).
            float v[Lc];
            {
                const float4* rowv = (const float4*)(xs[buf] + c * Lc);
                #pragma unroll
                for (int i = 0; i < Lc / 4; ++i) {
                    const float4 q = rowv[i];
                    v[4*i+0] = q.x; v[4*i+1] = q.y; v[4*i+2] = q.z; v[4*i+3] = q.w;
                }
            }

            float* op = out + (size_t)(pos0 + p) * OUT_CH + t * CH_PER_T;
            #pragma unroll
            for (int j = 0; j < CH_PER_T; ++j) {
                const float w0 = w[3*j + 0];
                const float w1 = w[3*j + 1];
                const float w2 = w[3*j + 2];

                // Running max, two windows per step -> v_max3 fusion; no cv array.
                float m = fmaf(v[0], w0, fmaf(v[1], w1, v[2] * w2));
                #pragma unroll
                for (int q = 1; q + 1 < CONV_LEN; q += 2) {
                    const float a = fmaf(v[q],   w0, fmaf(v[q+1], w1, v[q+2] * w2));
                    const float b = fmaf(v[q+1], w0, fmaf(v[q+2], w1, v[q+3] * w2));
                    m = fmaxf(fmaxf(m, a), b);
                }
                m = fmaxf(m, fmaf(v[CONV_LEN-1], w0,
                           fmaf(v[CONV_LEN],     w1, v[CONV_LEN+1] * w2)));

                op[j] = m + bb[j];      // bias hoisted past max (window-invariant)
            }
        }

        // Stage slab p+1 into the other buffer; barrier separates it from readers.
        if (stg && (p + 1 < NP))
            ((float4*)xs[buf ^ 1])[t] = preA;

        if (p + 1 < NP) block_sync();   // lgkmcnt-only: prefetch survives barrier
    }
}

extern "C" void kernel_launch(void* const* d_in, const int* in_sizes, int n_in,
                              void* d_out, int out_size, void* d_ws, size_t ws_size,
                              hipStream_t stream) {
    const float* x      = (const float*)d_in[0];  // [B,S,C,L] fp32
    const float* weight = (const float*)d_in[1];  // [C*F,1,W] fp32
    const float* bias   = (const float*)d_in[2];  // [C*F] fp32
    float* out          = (float*)d_out;          // [B,S,C*F] fp32

    const int nBlocks = (Bc * Sc) / NP;           // 1024 blocks = 1 residency round
    charcnn_kernel<<<nBlocks, BLOCK, 0, stream>>>(x, weight, bias, out);
}

// Round 14
// 27.372 us; speedup vs baseline: 1.0651x; 1.0651x over previous
//
#include <hip/hip_runtime.h>

// Problem constants (from reference): B=32, S=256, C=50, L=20, F=30, W=3
constexpr int Bc = 32;
constexpr int Sc = 256;
constexpr int Cc = 50;
constexpr int Lc = 20;
constexpr int Fc = 30;
constexpr int Wc = 3;
constexpr int OUT_CH   = Cc * Fc;       // 1500
constexpr int CONV_LEN = Lc - Wc + 1;   // 18
constexpr int XSZ      = Cc * Lc;       // 1000 floats per (b,s)
constexpr int BLOCK    = 512;           // 8 waves/block
constexpr int CH_PER_T = 3;             // 3t..3t+2 never crosses a group boundary
constexpr int NP       = 8;             // positions per block -> 1024 blocks, 1 round
constexpr int ACT      = OUT_CH / CH_PER_T;   // 500 active compute lanes
constexpr int STG      = XSZ / 4;             // 250 stager lanes (float4 each)

// Best-known configuration (R8, 27.53 us). R9-R12 variations (persistent
// blocks, wave-autonomous global_load_lds, packed math, entry stagger) were
// all null or worse; restoring this exact kernel.

// Barrier with lgkmcnt(0) only: retires this wave's own ds ops (RAW visibility
// + WAR on shared buffers); global prefetch loads stay in flight across it.
static __device__ __forceinline__ void block_sync() {
    asm volatile("s_waitcnt lgkmcnt(0)" ::: "memory");
    __builtin_amdgcn_s_barrier();
    asm volatile("" ::: "memory");
}

// __launch_bounds__(512, 8): 8 waves/EU minimum -> compiler MUST fit 64 VGPRs.
// 4 blocks/CU x 8 waves = 32 waves/CU (max occupancy); LDS 8KB -> not limiting.
__global__ __launch_bounds__(BLOCK, 8)
void charcnn_kernel(const float* __restrict__ x,      // [B*S, C, L]
                    const float* __restrict__ weight, // [C*F, 1, W]
                    const float* __restrict__ bias,   // [C*F]
                    float* __restrict__ out)          // [B*S, C*F]
{
    __shared__ float xs[2][XSZ];        // double-buffered 4 KB slabs

    const int t    = threadIdx.x;
    const int pos0 = blockIdx.x * NP;
    const bool on  = (t < ACT);         // 500 compute lanes
    const bool stg = (t < STG);         // 250 staging lanes

    // ---- weights/bias once per thread: 9 + 3 scalars (register-lean)
    float w[CH_PER_T * Wc];             // 9 floats at weight + 9t
    float bb[CH_PER_T];
    if (on) {
        const float* wp = weight + t * (CH_PER_T * Wc);
        #pragma unroll
        for (int i = 0; i < CH_PER_T * Wc; ++i) w[i] = wp[i];
        const float* bp = bias + t * CH_PER_T;
        #pragma unroll
        for (int i = 0; i < CH_PER_T; ++i) bb[i] = bp[i];
    }

    const int c = t / 10;               // group shared by this thread's 3 channels

    // ---- prologue: stage slab0 into xs[0]
    if (stg)
        ((float4*)xs[0])[t] = ((const float4*)(x + (size_t)pos0 * XSZ))[t];
    block_sync();

    #pragma unroll 2                    // static buf indices, modest code size
    for (int p = 0; p < NP; ++p) {
        const int buf = p & 1;

        // Issue next slab's load FIRST: latency hides under this position's compute.
        float4 preA;
        if (stg && (p + 1 < NP))
            preA = ((const float4*)(x + (size_t)(pos0 + p + 1) * XSZ))[t];

        if (on) {
            // Row: 80 B, 16B-aligned -> 5x ds_read_b128 (10 lanes share a row).
            float v[Lc];
            {
                const float4* rowv = (const float4*)(xs[buf] + c * Lc);
                #pragma unroll
                for (int i = 0; i < Lc / 4; ++i) {
                    const float4 q = rowv[i];
                    v[4*i+0] = q.x; v[4*i+1] = q.y; v[4*i+2] = q.z; v[4*i+3] = q.w;
                }
            }

            float* op = out + (size_t)(pos0 + p) * OUT_CH + t * CH_PER_T;
            #pragma unroll
            for (int j = 0; j < CH_PER_T; ++j) {
                const float w0 = w[3*j + 0];
                const float w1 = w[3*j + 1];
                const float w2 = w[3*j + 2];

                // Running max, two windows per step -> v_max3 fusion; no cv array.
                float m = fmaf(v[0], w0, fmaf(v[1], w1, v[2] * w2));
                #pragma unroll
                for (int q = 1; q + 1 < CONV_LEN; q += 2) {
                    const float a = fmaf(v[q],   w0, fmaf(v[q+1], w1, v[q+2] * w2));
                    const float b = fmaf(v[q+1], w0, fmaf(v[q+2], w1, v[q+3] * w2));
                    m = fmaxf(fmaxf(m, a), b);
                }
                m = fmaxf(m, fmaf(v[CONV_LEN-1], w0,
                           fmaf(v[CONV_LEN],     w1, v[CONV_LEN+1] * w2)));

                op[j] = m + bb[j];      // bias hoisted past max (window-invariant)
            }
        }

        // Stage slab p+1 into the other buffer; barrier separates it from readers.
        if (stg && (p + 1 < NP))
            ((float4*)xs[buf ^ 1])[t] = preA;

        if (p + 1 < NP) block_sync();   // lgkmcnt-only: prefetch survives barrier
    }
}

extern "C" void kernel_launch(void* const* d_in, const int* in_sizes, int n_in,
                              void* d_out, int out_size, void* d_ws, size_t ws_size,
                              hipStream_t stream) {
    const float* x      = (const float*)d_in[0];  // [B,S,C,L] fp32
    const float* weight = (const float*)d_in[1];  // [C*F,1,W] fp32
    const float* bias   = (const float*)d_in[2];  // [C*F] fp32
    float* out          = (float*)d_out;          // [B,S,C*F] fp32

    const int nBlocks = (Bc * Sc) / NP;           // 1024 blocks = 1 residency round
    charcnn_kernel<<<nBlocks, BLOCK, 0, stream>>>(x, weight, bias, out);
}